// Round 17
// baseline (5749.810 us; speedup 1.0000x reference)
//
#include <hip/hip_runtime.h>

typedef unsigned short u16;
typedef unsigned int u32;
typedef short bs8 __attribute__((ext_vector_type(8)));
typedef float f4_t __attribute__((ext_vector_type(4)));

#define NB   32
#define TSEQ 512
#define TENC 1024
#define HD   1024
#define VOC  512
#define FS   32          // flag stride in dwords (128B)
#define POLL_CAP (1 << 22)

#define AS1 __attribute__((address_space(1)))
#define AS3 __attribute__((address_space(3)))

__device__ __forceinline__ float b2f(u16 u) {
  union { u32 i; float f; } x; x.i = ((u32)u) << 16; return x.f;
}
__device__ __forceinline__ u16 f2b(float f) {
  union { float ff; u32 i; } x; x.ff = f;
  u32 r = x.i + 0x7fff + ((x.i >> 16) & 1);   // RNE
  return (u16)(r >> 16);
}
__device__ __forceinline__ float inF(const void* p, size_t i, int bf) {
  return bf ? b2f(((const u16*)p)[i]) : ((const float*)p)[i];
}
__device__ __forceinline__ void inF4(const void* p, size_t i, int bf, float* o) {
  if (bf) {
    ushort4 u = *reinterpret_cast<const ushort4*>((const u16*)p + i);
    o[0] = b2f(u.x); o[1] = b2f(u.y); o[2] = b2f(u.z); o[3] = b2f(u.w);
  } else {
    float4 v = *reinterpret_cast<const float4*>((const float*)p + i);
    o[0] = v.x; o[1] = v.y; o[2] = v.z; o[3] = v.w;
  }
}
__device__ __forceinline__ void outF(void* p, size_t i, float v, int bf) {
  if (bf) ((u16*)p)[i] = f2b(v);
  else ((float*)p)[i] = v;
}
__device__ __forceinline__ void gld16(const void* g, void* l) {
  __builtin_amdgcn_global_load_lds((const AS1 u32*)g, (AS3 u32*)l, 16, 0, 0);
}
// coherent (MALL) direct-to-LDS load: CPol SC0|SC1 = 0x11 bypasses the XCD L2
__device__ __forceinline__ void gld16c(const void* g, void* l) {
  __builtin_amdgcn_global_load_lds((const AS1 u32*)g, (AS3 u32*)l, 16, 0, 0x11);
}
// --- coherence-point (MALL) scalar accesses ---
__device__ __forceinline__ u32 aLoad(u32* p) {
  return __hip_atomic_load(p, __ATOMIC_RELAXED, __HIP_MEMORY_SCOPE_AGENT);
}
__device__ __forceinline__ void aStore(u32* p, u32 v) {
  __hip_atomic_store(p, v, __ATOMIC_RELAXED, __HIP_MEMORY_SCOPE_AGENT);
}
__device__ __forceinline__ void stUCshort(char* p, u32 v) {
  asm volatile("global_store_short %0, %1, off sc0 sc1" :: "v"(p), "v"(v) : "memory");
}
__device__ __forceinline__ void waitVM0() {
  asm volatile("s_waitcnt vmcnt(0)" ::: "memory");
}

// ---------------- dtype detect ----------------
__global__ void k_detect(const u32* __restrict__ w, int* __restrict__ flag) {
  __shared__ int cnt;
  if (threadIdx.x == 0) cnt = 0;
  __syncthreads();
  int c = 0;
  for (int i = threadIdx.x; i < 1024; i += 256) {
    u32 e = (w[i] >> 7) & 0xFF;
    if (e >= 100 && e <= 126) c++;
  }
  atomicAdd(&cnt, c);
  __syncthreads();
  if (threadIdx.x == 0) flag[0] = (cnt >= 512) ? 1 : 0;
}

// ---------------- generic f32|bf16 -> bf16 convert ----------------
__global__ __launch_bounds__(256) void k_f2bf(
    const void* __restrict__ in, u16* __restrict__ out, const int* __restrict__ flagp) {
  const int bf = flagp[0];
  size_t i = ((size_t)blockIdx.x * 256 + threadIdx.x) * 4;
  float v[4]; inF4(in, i, bf, v);
  ushort4 o; o.x = f2b(v[0]); o.y = f2b(v[1]); o.z = f2b(v[2]); o.w = f2b(v[3]);
  *reinterpret_cast<ushort4*>(&out[i]) = o;
}

// ---------------- embedding gather (with SOS prepend) -> bf16 x ----------------
__global__ __launch_bounds__(256) void k_embed(
    const int* __restrict__ labels, const void* __restrict__ emb,
    u16* __restrict__ x, const int* __restrict__ flagp) {
  const int bf = flagp[0];
  const int m = blockIdx.x;            // m = b*512 + t
  const int b = m >> 9, t = m & 511;
  const int lab = (t == 0) ? 0 : labels[b * 511 + t - 1];
  const size_t src = (size_t)lab * HD;
  const size_t dst = (size_t)m * HD;
  const int k = threadIdx.x * 4;
  float v[4]; inF4(emb, src + k, bf, v);
  ushort4 o; o.x = f2b(v[0]); o.y = f2b(v[1]); o.z = f2b(v[2]); o.w = f2b(v[3]);
  *reinterpret_cast<ushort4*>(&x[dst + k]) = o;
}

// ---------------- enc transpose: [b][t][h] -> [b][h][t] bf16 ----------------
__global__ __launch_bounds__(256) void k_transpose(
    const void* __restrict__ enc, u16* __restrict__ encT, const int* __restrict__ flagp) {
  const int bf = flagp[0];
  __shared__ float tile[32][33];
  const int b = blockIdx.z, t0 = blockIdx.x * 32, h0 = blockIdx.y * 32;
  const int i = threadIdx.x >> 5, j = threadIdx.x & 31;
  const size_t base = (size_t)b * (TENC * HD);
#pragma unroll
  for (int rr = 0; rr < 4; rr++) {
    int r = i + rr * 8;
    tile[r][j] = inF(enc, base + (size_t)(t0 + r) * HD + h0 + j, bf);
  }
  __syncthreads();
#pragma unroll
  for (int rr = 0; rr < 4; rr++) {
    int r = i + rr * 8;
    encT[base + (size_t)(h0 + r) * TENC + t0 + j] = f2b(tile[j][r]);
  }
}

// ---------------- MFMA GEMM: C[m][n] = act(sum_k A[m][k]*B[n][k] + bias[n]) ----------------
// cmode: 0 = bf16 row-major, 1 = f32 row-major, 2 = bf16 t-major ((row&511)*32+(row>>9))
__global__ __launch_bounds__(256) void k_mfma_gemm(
    const u16* __restrict__ A, const u16* __restrict__ Bm, int K, int lda, int ldb,
    long strideA, long strideB, long strideC,
    void* __restrict__ C, int ldc, int cmode, int act,
    const void* __restrict__ bias, const int* __restrict__ flagp) {
  const int bf = flagp[0];
  __shared__ u16 lsA[8192];
  __shared__ u16 lsB[8192];
  const int tid = threadIdx.x;
  const int l = tid & 63, w = tid >> 6;
  const int wr = w >> 1, wc = w & 1;
  const long m0 = (long)blockIdx.x * 128;
  const long n0 = (long)blockIdx.y * 128;
  const long bz = blockIdx.z;
  const u16* Ab = A + bz * strideA;
  const u16* Bb = Bm + bz * strideB;

  f4_t acc[4][4] = {};
  const int srow = w * 8 + (l >> 3);
  const int schx = (l & 7) * 16;

  for (int kt = 0; kt < K; kt += 64) {
#pragma unroll
    for (int i = 0; i < 4; i++) {
      const int row = i * 32 + srow;
      const char* ga = (const char*)(Ab + (m0 + row) * (long)lda + kt)
                       + (schx ^ ((row & 7) << 4));
      gld16(ga, (char*)lsA + i * 4096 + w * 1024);
    }
#pragma unroll
    for (int i = 0; i < 4; i++) {
      const int row = i * 32 + srow;
      const char* gb = (const char*)(Bb + (n0 + row) * (long)ldb + kt)
                       + (schx ^ ((row & 7) << 4));
      gld16(gb, (char*)lsB + i * 4096 + w * 1024);
    }
    __syncthreads();
#pragma unroll
    for (int h = 0; h < 2; h++) {
      bs8 af[4], bfr[4];
#pragma unroll
      for (int i = 0; i < 4; i++) {
        const int row = wr * 64 + i * 16 + (l & 15);
        const int byt = row * 128 + (((h * 64) + ((l >> 4) * 16)) ^ ((row & 7) << 4));
        af[i] = *(const bs8*)((const char*)lsA + byt);
      }
#pragma unroll
      for (int j = 0; j < 4; j++) {
        const int row = wc * 64 + j * 16 + (l & 15);
        const int byt = row * 128 + (((h * 64) + ((l >> 4) * 16)) ^ ((row & 7) << 4));
        bfr[j] = *(const bs8*)((const char*)lsB + byt);
      }
#pragma unroll
      for (int i = 0; i < 4; i++)
#pragma unroll
        for (int j = 0; j < 4; j++)
          acc[i][j] = __builtin_amdgcn_mfma_f32_16x16x32_bf16(af[i], bfr[j], acc[i][j], 0, 0, 0);
    }
    __syncthreads();
  }

  float bv[4] = {0.f, 0.f, 0.f, 0.f};
  if (bias) {
#pragma unroll
    for (int j = 0; j < 4; j++)
      bv[j] = inF(bias, (size_t)(n0 + wc * 64 + j * 16 + (l & 15)), bf);
  }
#pragma unroll
  for (int i = 0; i < 4; i++) {
#pragma unroll
    for (int j = 0; j < 4; j++) {
      const long rowb = m0 + wr * 64 + i * 16 + ((l >> 4) * 4);
      const long col = n0 + wc * 64 + j * 16 + (l & 15);
#pragma unroll
      for (int r = 0; r < 4; r++) {
        float v = acc[i][j][r] + bv[j];
        if (act == 1) v = tanhf(v);
        const long row = rowb + r;
        if (cmode == 0) {
          ((u16*)C)[bz * strideC + row * (long)ldc + col] = f2b(v);
        } else if (cmode == 1) {
          ((float*)C)[bz * strideC + row * (long)ldc + col] = v;
        } else {
          ((u16*)C)[((long)(row & 511) * 32 + (row >> 9)) * (long)ldc + col] = f2b(v);
        }
      }
    }
  }
}

// ---------------- masked softmax over T_ENC (in-place bf16) ----------------
__global__ __launch_bounds__(256) void k_softmax(
    u16* __restrict__ S, const int* __restrict__ lens) {
  const int m = blockIdx.x;
  const int b = m >> 9;
  const int len = lens[b];
  const int tid = threadIdx.x;
  const size_t base = (size_t)m * TENC;
  float v[4];
  float mx = -1e30f;
#pragma unroll
  for (int i = 0; i < 4; i++) {
    int j = tid + i * 256;
    float s = b2f(S[base + j]);
    v[i] = (j < len) ? s : -1e30f;
    mx = fmaxf(mx, v[i]);
  }
  __shared__ float red[8];
  for (int o = 32; o; o >>= 1) mx = fmaxf(mx, __shfl_xor(mx, o, 64));
  if ((tid & 63) == 0) red[tid >> 6] = mx;
  __syncthreads();
  mx = fmaxf(fmaxf(red[0], red[1]), fmaxf(red[2], red[3]));
  float e[4]; float sum = 0.f;
#pragma unroll
  for (int i = 0; i < 4; i++) {
    e[i] = (v[i] > -1e29f) ? expf(v[i] - mx) : 0.f;
    sum += e[i];
  }
  for (int o = 32; o; o >>= 1) sum += __shfl_xor(sum, o, 64);
  __shared__ float red2[8];
  if ((tid & 63) == 0) red2[tid >> 6] = sum;
  __syncthreads();
  sum = red2[0] + red2[1] + red2[2] + red2[3];
  const float inv = 1.f / sum;
#pragma unroll
  for (int i = 0; i < 4; i++) S[base + tid + i * 256] = f2b(e[i] * inv);
}

// ---------------- pack weights into per-block MFMA fragment order ----------------
// virtual col v = blk*32 + c16*16 + (lane&15); feature f=v>>2; slot=v&3
// fused=0 (L0): 128 blks, K=1024 (Whh; r,z,n,zero)           [blk][c16(2)][ks(32)][l][8] 64KB/blk
// fused=1 (L1): 128 blks, K=2048 ([Wih;Whh]; r,z,n_ih,n_hh)  [blk][c16(2)][ks(64)][l][8] 128KB/blk
__global__ __launch_bounds__(256) void k_packw(
    const void* __restrict__ Wih, const void* __restrict__ Whh,
    u16* __restrict__ out, int fused, const int* __restrict__ flagp) {
  const int bf = flagp[0];
  const long idx = (long)blockIdx.x * 256 + threadIdx.x;
  const int l = (int)(idx & 63);
  int ks, c16, blk;
  if (fused) { ks = (int)((idx >> 6) & 63); c16 = (int)((idx >> 12) & 1); blk = (int)(idx >> 13); }
  else       { ks = (int)((idx >> 6) & 31); c16 = (int)((idx >> 11) & 1); blk = (int)(idx >> 12); }
  const int v = blk * 32 + c16 * 16 + (l & 15);
  const int f = v >> 2, slot = v & 3;
  const int k = ks * 32 + ((l >> 4) << 3);
  const void* W = Whh; long row = 0; bool zero = false; int kk = k;
  if (!fused) {
    if (slot == 0) row = f;
    else if (slot == 1) row = 1024 + f;
    else if (slot == 2) row = 2048 + f;
    else zero = true;
  } else {
    const bool xp = (k < 1024); kk = k & 1023;
    W = xp ? Wih : Whh;
    if (slot == 0) row = f;
    else if (slot == 1) row = 1024 + f;
    else if (slot == 2) { row = 2048 + f; zero = !xp; }
    else { row = 2048 + f; zero = xp; }
  }
  u16 o[8];
#pragma unroll
  for (int e = 0; e < 8; e++)
    o[e] = zero ? (u16)0 : f2b(inF(W, (size_t)row * 1024 + kk + e, bf));
  ushort4* dst = (ushort4*)(out + idx * 8);
  dst[0] = make_ushort4(o[0], o[1], o[2], o[3]);
  dst[1] = make_ushort4(o[4], o[5], o[6], o[7]);
}

// ---------------- persistent 2-layer GRU (r14 structure + split-wait/prefetch overlap) ----------------
__device__ __forceinline__ void stage64_issue(const char* src, char* dst, int l, int w) {
#pragma unroll
  for (int i = 0; i < 16; i++) {
    const int off = i * 4096 + w * 1024;
    gld16c(src + off + l * 16, dst + off);
  }
}
// wait on one 128-flag group starting at `base`
__device__ __forceinline__ void waitgrp(u32* flags, int base, int target, int tid) {
  if (tid < 64) {
    int guard = 0;
    while (1) {
      const int v0 = (int)aLoad(flags + (size_t)(base + tid) * FS);
      const int v1 = (int)aLoad(flags + (size_t)(base + tid + 64) * FS);
      const bool ok = (v0 >= target) && (v1 >= target);
      if (__all(ok)) break;
      if (++guard > POLL_CAP) break;
      __builtin_amdgcn_s_sleep(1);
    }
  }
  __syncthreads();
}

__global__ void __launch_bounds__(256, 1) k_gru_p(
    const u16* __restrict__ xp0, const u16* __restrict__ wpk0, const u16* __restrict__ wpk1,
    const void* __restrict__ bhh0, const void* __restrict__ bih1, const void* __restrict__ bhh1,
    u16* __restrict__ y1, char* h0buf, char* h1buf, u32* flags,
    const int* __restrict__ flagp) {
  extern __shared__ char smem[];            // L0: [W 64K][img 64K][red]; L1: [img 128K][red]
  float* red = (float*)(smem + 131072);
  const int bf = flagp[0];
  const int tid = threadIdx.x, l = tid & 63, w = tid >> 6;
  const int nh = w & 1, kh = w >> 1;
  const int g = blockIdx.x;
  const bool isL0 = (g < 128);
  const int gg = isL0 ? g : g - 128;
  const int fl = (l & 15) >> 2;
  const int F = gg * 8 + nh * 4 + fl;
  const int bl0 = (l & 48) | (fl << 2);

  float hprev[2][4] = {{0.f, 0.f, 0.f, 0.f}, {0.f, 0.f, 0.f, 0.f}};

  if (isL0) {
    {  // ONE-TIME: stage 64KB Whh slice into LDS (normal cached DMA)
      const char* wsrc = (const char*)(wpk0 + (size_t)gg * 32768);
#pragma unroll
      for (int i = 0; i < 16; i++) {
        const int off = i * 4096 + w * 1024;
        gld16(wsrc + off + l * 16, smem + off);
      }
    }
    __syncthreads();
    const char* Wl = smem;         // 64KB weights (LDS)
    char* img = smem + 65536;      // 64KB h image
    const float br = inF(bhh0, (size_t)F, bf);
    const float bz = inF(bhh0, (size_t)(1024 + F), bf);
    const float bn = inF(bhh0, (size_t)(2048 + F), bf);
    for (int t = 0; t < TSEQ; t++) {
      // own grp done t-1 (binding); L1 freed slot (t-1)
      waitgrp(flags, 0, t, tid);
      waitgrp(flags, 128, t - 1, tid);
      // prefetch xp into regs (kh==0 lanes), then issue stage DMA; one drain covers both
      float xr[2][4], xz[2][4], xn[2][4];
      if (kh == 0) {
#pragma unroll
        for (int mt = 0; mt < 2; mt++)
#pragma unroll
          for (int r = 0; r < 4; r++) {
            const int b = mt * 16 + ((l >> 4) << 2) + r;
            const long xb = (long)t * 98304 + (long)b * 3072 + F;
            xr[mt][r] = b2f(xp0[xb]);
            xz[mt][r] = b2f(xp0[xb + 1024]);
            xn[mt][r] = b2f(xp0[xb + 2048]);
          }
      }
      stage64_issue(h0buf + (t & 1) * 65536, img, l, w);
      waitVM0();
      __syncthreads();
      f4_t S[2] = {};
#pragma unroll 4
      for (int ksl = 0; ksl < 16; ksl++) {
        const int ks = kh * 16 + ksl;
        const bs8 bb = *(const bs8*)(Wl + (((size_t)(nh * 32 + ks) * 64 + l) << 4));
#pragma unroll
        for (int mt = 0; mt < 2; mt++) {
          const int row = mt * 16 + (l & 15);
          const int byt = row * 2048 + ((ks * 64 + ((l >> 4) << 4)) ^ ((row & 7) << 4));
          const bs8 aa = *(const bs8*)(img + byt);
          S[mt] = __builtin_amdgcn_mfma_f32_16x16x32_bf16(aa, bb, S[mt], 0, 0, 0);
        }
      }
      if (kh == 1) {
#pragma unroll
        for (int mt = 0; mt < 2; mt++)
          *(f4_t*)&red[((nh * 2 + mt) * 64 + l) * 4] = S[mt];
      }
      __syncthreads();
      if (kh == 0) {
#pragma unroll
        for (int mt = 0; mt < 2; mt++)
          S[mt] += *(const f4_t*)&red[((nh * 2 + mt) * 64 + l) * 4];
        char* hw = h0buf + ((t + 1) & 1) * 65536;
#pragma unroll
        for (int mt = 0; mt < 2; mt++) {
#pragma unroll
          for (int r = 0; r < 4; r++) {
            const int b = mt * 16 + ((l >> 4) << 2) + r;
            const float hr = __shfl(S[mt][r], bl0);
            const float hz = __shfl(S[mt][r], bl0 + 1);
            const float hn = __shfl(S[mt][r], bl0 + 2);
            const float rr = 1.f / (1.f + expf(-(xr[mt][r] + hr + br)));
            const float zz = 1.f / (1.f + expf(-(xz[mt][r] + hz + bz)));
            const float nn = tanhf(xn[mt][r] + rr * (hn + bn));
            const float hv = (1.f - zz) * nn + zz * hprev[mt][r];
            hprev[mt][r] = hv;
            if ((l & 3) == 0) {
              const int swb = b * 2048 + ((2 * F) ^ ((b & 7) << 4));
              stUCshort(hw + swb, (u32)f2b(hv));
            }
          }
        }
      }
      waitVM0();
      __syncthreads();
      if (tid == 0) aStore(flags + (size_t)g * FS, (u32)(t + 1));
    }
  } else {
    const char* W = (const char*)(wpk1 + (size_t)gg * 65536);  // 128KB slice (L2)
    const float br = inF(bih1, (size_t)F, bf) + inF(bhh1, (size_t)F, bf);
    const float bz = inF(bih1, (size_t)(1024 + F), bf) + inF(bhh1, (size_t)(1024 + F), bf);
    const float bxn = inF(bih1, (size_t)(2048 + F), bf);
    const float bhn = inF(bhh1, (size_t)(2048 + F), bf);
    for (int s = 0; s < TSEQ; s++) {
      // split wait: own group (fast) -> stage h1 early; then L0 (binding) -> stage y0
      waitgrp(flags, 128, s, tid);                               // own grp done s-1
      stage64_issue(h1buf + (s & 1) * 65536, smem + 65536, l, w);   // h1 image (in flight)
      waitgrp(flags, 0, s + 1, tid);                             // y0[s]=h0(s+1) ready
      stage64_issue(h0buf + ((s + 1) & 1) * 65536, smem, l, w);     // y0 image
      waitVM0();
      __syncthreads();
      f4_t S[2] = {};
#pragma unroll 4
      for (int ksl = 0; ksl < 32; ksl++) {
        const int ks = kh * 32 + ksl;
        const bs8 bb = *(const bs8*)(W + (((size_t)(nh * 64 + ks) * 64 + l) << 4));
        const int base = (ks >= 32) ? 65536 : 0;
        const int ks5 = ks & 31;
#pragma unroll
        for (int mt = 0; mt < 2; mt++) {
          const int row = mt * 16 + (l & 15);
          const int byt = base + row * 2048 + ((ks5 * 64 + ((l >> 4) << 4)) ^ ((row & 7) << 4));
          const bs8 aa = *(const bs8*)(smem + byt);
          S[mt] = __builtin_amdgcn_mfma_f32_16x16x32_bf16(aa, bb, S[mt], 0, 0, 0);
        }
      }
      if (kh == 1) {
#pragma unroll
        for (int mt = 0; mt < 2; mt++)
          *(f4_t*)&red[((nh * 2 + mt) * 64 + l) * 4] = S[mt];
      }
      __syncthreads();
      if (kh == 0) {
#pragma unroll
        for (int mt = 0; mt < 2; mt++)
          S[mt] += *(const f4_t*)&red[((nh * 2 + mt) * 64 + l) * 4];
        char* hw = h1buf + ((s + 1) & 1) * 65536;
#pragma unroll
        for (int mt = 0; mt < 2; mt++) {
#pragma unroll
          for (int r = 0; r < 4; r++) {
            const int b = mt * 16 + ((l >> 4) << 2) + r;
            const float rs = __shfl(S[mt][r], bl0);
            const float zs = __shfl(S[mt][r], bl0 + 1);
            const float xnp = __shfl(S[mt][r], bl0 + 2);
            const float hnp = __shfl(S[mt][r], bl0 + 3);
            const float rr = 1.f / (1.f + expf(-(rs + br)));
            const float zz = 1.f / (1.f + expf(-(zs + bz)));
            const float nn = tanhf((xnp + bxn) + rr * (hnp + bhn));
            const float hv = (1.f - zz) * nn + zz * hprev[mt][r];
            hprev[mt][r] = hv;
            if ((l & 3) == 0) {
              const int swb = b * 2048 + ((2 * F) ^ ((b & 7) << 4));
              stUCshort(hw + swb, (u32)f2b(hv));
              y1[((long)b * 512 + s) * 1024 + F] = f2b(hv);   // normal store
            }
          }
        }
      }
      waitVM0();
      __syncthreads();
      if (tid == 0) aStore(flags + (size_t)g * FS, (u32)(s + 1));
    }
  }
}

// ---------------- log_softmax over V ----------------
__global__ __launch_bounds__(256) void k_logsoftmax(
    const float* __restrict__ L, void* __restrict__ out, const int* __restrict__ flagp) {
  const int bf = flagp[0];
  const int m = blockIdx.x;
  const int tid = threadIdx.x;
  const size_t base = (size_t)m * VOC;
  float v0 = L[base + tid], v1 = L[base + tid + 256];
  float mx = fmaxf(v0, v1);
  __shared__ float red[8];
  for (int o = 32; o; o >>= 1) mx = fmaxf(mx, __shfl_xor(mx, o, 64));
  if ((tid & 63) == 0) red[tid >> 6] = mx;
  __syncthreads();
  mx = fmaxf(fmaxf(red[0], red[1]), fmaxf(red[2], red[3]));
  float s = expf(v0 - mx) + expf(v1 - mx);
  for (int o = 32; o; o >>= 1) s += __shfl_xor(s, o, 64);
  __shared__ float red2[8];
  if ((tid & 63) == 0) red2[tid >> 6] = s;
  __syncthreads();
  s = red2[0] + red2[1] + red2[2] + red2[3];
  const float lse = mx + logf(s);
  outF(out, base + tid, v0 - lse, bf);
  outF(out, base + tid + 256, v1 - lse, bf);
}

extern "C" void kernel_launch(void* const* d_in, const int* in_sizes, int n_in,
                              void* d_out, int out_size, void* d_ws, size_t ws_size,
                              hipStream_t stream) {
  const void* enc = d_in[0];
  const int* lens = (const int*)d_in[1];
  const int* labels = (const int*)d_in[2];
  const void* emb = d_in[3];
  const void* lin_in = d_in[4];
  const void* lin_out = d_in[5];
  const void* w_ih0 = d_in[6];
  const void* w_hh0 = d_in[7];
  const void* b_ih0 = d_in[8];
  const void* b_hh0 = d_in[9];
  const void* w_ih1 = d_in[10];
  const void* w_hh1 = d_in[11];
  const void* b_ih1 = d_in[12];
  const void* b_hh1 = d_in[13];
  const void* fc_w = d_in[14];
  const void* fc_b = d_in[15];

  char* ws = (char*)d_ws;
  const size_t SZ = (size_t)NB * TSEQ * HD * 2;   // 33,554,432
  int* flag = (int*)ws;
  u16* R0 = (u16*)(ws + 256);                     // x -> encT -> attn
  u16* R1 = (u16*)(ws + 256 + SZ);                // enc_bf -> wih0_bf
  u16* R2 = (u16*)(ws + 256 + 2 * SZ);            // combined -> [y1 | packs + h]
  char* R4 = ws + 256 + 4 * SZ;                   // scores+wli/wlo -> xp0 -> wfc+logits

  char* R2u = (char*)R2 + SZ;
  u16* wpk0 = (u16*)R2u;                          // 8 MB  (128 blk x 64KB)
  u16* wpk1 = (u16*)(R2u + 8388608);              // 16 MB (128 blk x 128KB)
  char* hreg = R2u + 25165824;
  u32* flagsbuf = (u32*)hreg;                     // 256*128B = 32KB
  char* h0buf = hreg + 32768;                     // 2 x 64KB parity
  char* h1buf = hreg + 32768 + 131072;            // 2 x 64KB parity
  const size_t hreg_bytes = 32768 + 262144;

  u16* scores = (u16*)R4;
  u16* wli = (u16*)(R4 + 35651584);
  u16* wlo = (u16*)(R4 + 37748736);
  u16* xp0 = (u16*)R4;                            // [t][b][3072] bf16, 96MB
  u16* wfc = (u16*)R4;                            // post-GRU, 1MB
  float* logits = (float*)(R4 + 1048576);         // post-GRU, 33.5MB f32

  k_detect<<<1, 256, 0, stream>>>((const u32*)emb, flag);
  k_embed<<<NB * TSEQ, 256, 0, stream>>>(labels, emb, R0, flag);
  k_f2bf<<<32768, 256, 0, stream>>>(enc, R1, flag);
  k_f2bf<<<1024, 256, 0, stream>>>(lin_in, wli, flag);
  k_f2bf<<<2048, 256, 0, stream>>>(lin_out, wlo, flag);

  // q = x @ lin_in^T -> combined right half
  k_mfma_gemm<<<dim3(128, 8, 1), 256, 0, stream>>>(
      R0, wli, HD, HD, HD, 0, 0, 0, (void*)(R2 + 1024), 2 * HD, 0, 0, nullptr, flag);
  // encT (x dead)
  k_transpose<<<dim3(32, 32, NB), 256, 0, stream>>>(enc, R0, flag);
  // scores[b] = q[b] @ enc_bf[b]^T
  k_mfma_gemm<<<dim3(4, 8, NB), 256, 0, stream>>>(
      R2 + 1024, R1, HD, 2 * HD, HD,
      (long)TSEQ * 2 * HD, (long)TENC * HD, (long)TSEQ * TENC,
      (void*)scores, TENC, 0, 0, nullptr, flag);
  k_softmax<<<NB * TSEQ, 256, 0, stream>>>(scores, lens);
  // mix[b] = w[b] @ encT[b]^T -> combined left half
  k_mfma_gemm<<<dim3(4, 8, NB), 256, 0, stream>>>(
      scores, R0, TENC, TENC, TENC,
      (long)TSEQ * TENC, (long)HD * TENC, (long)TSEQ * 2 * HD,
      (void*)R2, 2 * HD, 0, 0, nullptr, flag);
  // attn = tanh(combined @ lin_out^T) -> R0 row-major (encT dead)
  k_mfma_gemm<<<dim3(128, 8, 1), 256, 0, stream>>>(
      R2, wlo, 2 * HD, 2 * HD, 2 * HD, 0, 0, 0,
      (void*)R0, HD, 0, 1, nullptr, flag);

  // weight packs (combined dead -> R2 upper free)
  k_packw<<<2048, 256, 0, stream>>>(nullptr, w_hh0, wpk0, 0, flag);
  k_packw<<<4096, 256, 0, stream>>>(w_ih1, w_hh1, wpk1, 1, flag);
  // w_ih0 bf16 (enc_bf dead)
  k_f2bf<<<3072, 256, 0, stream>>>(w_ih0, R1, flag);
  // xp0 = attn @ w_ih0^T + b_ih0, t-major (overwrites scores/wli/wlo - all dead)
  k_mfma_gemm<<<dim3(128, 24, 1), 256, 0, stream>>>(
      R0, R1, HD, HD, HD, 0, 0, 0, (void*)xp0, 3 * HD, 2, 0, b_ih0, flag);

  // persistent fence-free GRU (split-wait overlap; coherent DMA staging; L0 W in LDS)
  hipMemsetAsync(hreg, 0, hreg_bytes, stream);
  hipFuncSetAttribute((const void*)k_gru_p,
                      hipFuncAttributeMaxDynamicSharedMemorySize, 139264);
  u16* y1p = R2;
  void* args[] = {&xp0, &wpk0, &wpk1,
                  (void*)&b_hh0, (void*)&b_ih1, (void*)&b_hh1,
                  &y1p, &h0buf, &h1buf, &flagsbuf, &flag};
  hipLaunchCooperativeKernel((const void*)k_gru_p, dim3(256), dim3(256),
                             args, 139264, stream);

  // logits = y1 @ fc_w^T + fc_b (xp0 dead)
  k_f2bf<<<512, 256, 0, stream>>>(fc_w, wfc, flag);
  k_mfma_gemm<<<dim3(128, 4, 1), 256, 0, stream>>>(
      R2, wfc, HD, HD, HD, 0, 0, 0, (void*)logits, VOC, 1, 0, fc_b, flag);
  k_logsoftmax<<<NB * TSEQ, 256, 0, stream>>>(logits, d_out, flag);
}

// Round 18
// 5134.365 us; speedup vs baseline: 1.1199x; 1.1199x over previous
//
#include <hip/hip_runtime.h>

typedef unsigned short u16;
typedef unsigned int u32;
typedef short bs8 __attribute__((ext_vector_type(8)));
typedef float f4_t __attribute__((ext_vector_type(4)));

#define NB   32
#define TSEQ 512
#define TENC 1024
#define HD   1024
#define VOC  512
#define FS   32          // flag stride in dwords (128B)
#define POLL_CAP (1 << 22)

#define AS1 __attribute__((address_space(1)))
#define AS3 __attribute__((address_space(3)))

__device__ __forceinline__ float b2f(u16 u) {
  union { u32 i; float f; } x; x.i = ((u32)u) << 16; return x.f;
}
__device__ __forceinline__ u16 f2b(float f) {
  union { float ff; u32 i; } x; x.ff = f;
  u32 r = x.i + 0x7fff + ((x.i >> 16) & 1);   // RNE
  return (u16)(r >> 16);
}
__device__ __forceinline__ float inF(const void* p, size_t i, int bf) {
  return bf ? b2f(((const u16*)p)[i]) : ((const float*)p)[i];
}
__device__ __forceinline__ void inF4(const void* p, size_t i, int bf, float* o) {
  if (bf) {
    ushort4 u = *reinterpret_cast<const ushort4*>((const u16*)p + i);
    o[0] = b2f(u.x); o[1] = b2f(u.y); o[2] = b2f(u.z); o[3] = b2f(u.w);
  } else {
    float4 v = *reinterpret_cast<const float4*>((const float*)p + i);
    o[0] = v.x; o[1] = v.y; o[2] = v.z; o[3] = v.w;
  }
}
__device__ __forceinline__ void outF(void* p, size_t i, float v, int bf) {
  if (bf) ((u16*)p)[i] = f2b(v);
  else ((float*)p)[i] = v;
}
__device__ __forceinline__ void gld16(const void* g, void* l) {
  __builtin_amdgcn_global_load_lds((const AS1 u32*)g, (AS3 u32*)l, 16, 0, 0);
}
// coherent (MALL) direct-to-LDS load: CPol SC0|SC1 = 0x11 bypasses the XCD L2
__device__ __forceinline__ void gld16c(const void* g, void* l) {
  __builtin_amdgcn_global_load_lds((const AS1 u32*)g, (AS3 u32*)l, 16, 0, 0x11);
}
// --- coherence-point (MALL) scalar accesses ---
__device__ __forceinline__ u32 aLoad(u32* p) {
  return __hip_atomic_load(p, __ATOMIC_RELAXED, __HIP_MEMORY_SCOPE_AGENT);
}
__device__ __forceinline__ void aStore(u32* p, u32 v) {
  __hip_atomic_store(p, v, __ATOMIC_RELAXED, __HIP_MEMORY_SCOPE_AGENT);
}
__device__ __forceinline__ void stUCshort(char* p, u32 v) {
  asm volatile("global_store_short %0, %1, off sc0 sc1" :: "v"(p), "v"(v) : "memory");
}
__device__ __forceinline__ void waitVM0() {
  asm volatile("s_waitcnt vmcnt(0)" ::: "memory");
}

// ---------------- dtype detect ----------------
__global__ void k_detect(const u32* __restrict__ w, int* __restrict__ flag) {
  __shared__ int cnt;
  if (threadIdx.x == 0) cnt = 0;
  __syncthreads();
  int c = 0;
  for (int i = threadIdx.x; i < 1024; i += 256) {
    u32 e = (w[i] >> 7) & 0xFF;
    if (e >= 100 && e <= 126) c++;
  }
  atomicAdd(&cnt, c);
  __syncthreads();
  if (threadIdx.x == 0) flag[0] = (cnt >= 512) ? 1 : 0;
}

// ---------------- generic f32|bf16 -> bf16 convert ----------------
__global__ __launch_bounds__(256) void k_f2bf(
    const void* __restrict__ in, u16* __restrict__ out, const int* __restrict__ flagp) {
  const int bf = flagp[0];
  size_t i = ((size_t)blockIdx.x * 256 + threadIdx.x) * 4;
  float v[4]; inF4(in, i, bf, v);
  ushort4 o; o.x = f2b(v[0]); o.y = f2b(v[1]); o.z = f2b(v[2]); o.w = f2b(v[3]);
  *reinterpret_cast<ushort4*>(&out[i]) = o;
}

// ---------------- embedding gather (with SOS prepend) -> bf16 x ----------------
__global__ __launch_bounds__(256) void k_embed(
    const int* __restrict__ labels, const void* __restrict__ emb,
    u16* __restrict__ x, const int* __restrict__ flagp) {
  const int bf = flagp[0];
  const int m = blockIdx.x;            // m = b*512 + t
  const int b = m >> 9, t = m & 511;
  const int lab = (t == 0) ? 0 : labels[b * 511 + t - 1];
  const size_t src = (size_t)lab * HD;
  const size_t dst = (size_t)m * HD;
  const int k = threadIdx.x * 4;
  float v[4]; inF4(emb, src + k, bf, v);
  ushort4 o; o.x = f2b(v[0]); o.y = f2b(v[1]); o.z = f2b(v[2]); o.w = f2b(v[3]);
  *reinterpret_cast<ushort4*>(&x[dst + k]) = o;
}

// ---------------- enc transpose: [b][t][h] -> [b][h][t] bf16 ----------------
__global__ __launch_bounds__(256) void k_transpose(
    const void* __restrict__ enc, u16* __restrict__ encT, const int* __restrict__ flagp) {
  const int bf = flagp[0];
  __shared__ float tile[32][33];
  const int b = blockIdx.z, t0 = blockIdx.x * 32, h0 = blockIdx.y * 32;
  const int i = threadIdx.x >> 5, j = threadIdx.x & 31;
  const size_t base = (size_t)b * (TENC * HD);
#pragma unroll
  for (int rr = 0; rr < 4; rr++) {
    int r = i + rr * 8;
    tile[r][j] = inF(enc, base + (size_t)(t0 + r) * HD + h0 + j, bf);
  }
  __syncthreads();
#pragma unroll
  for (int rr = 0; rr < 4; rr++) {
    int r = i + rr * 8;
    encT[base + (size_t)(h0 + r) * TENC + t0 + j] = f2b(tile[j][r]);
  }
}

// ---------------- MFMA GEMM: C[m][n] = act(sum_k A[m][k]*B[n][k] + bias[n]) ----------------
// cmode: 0 = bf16 row-major, 1 = f32 row-major, 2 = bf16 t-major ((row&511)*32+(row>>9))
__global__ __launch_bounds__(256) void k_mfma_gemm(
    const u16* __restrict__ A, const u16* __restrict__ Bm, int K, int lda, int ldb,
    long strideA, long strideB, long strideC,
    void* __restrict__ C, int ldc, int cmode, int act,
    const void* __restrict__ bias, const int* __restrict__ flagp) {
  const int bf = flagp[0];
  __shared__ u16 lsA[8192];
  __shared__ u16 lsB[8192];
  const int tid = threadIdx.x;
  const int l = tid & 63, w = tid >> 6;
  const int wr = w >> 1, wc = w & 1;
  const long m0 = (long)blockIdx.x * 128;
  const long n0 = (long)blockIdx.y * 128;
  const long bz = blockIdx.z;
  const u16* Ab = A + bz * strideA;
  const u16* Bb = Bm + bz * strideB;

  f4_t acc[4][4] = {};
  const int srow = w * 8 + (l >> 3);
  const int schx = (l & 7) * 16;

  for (int kt = 0; kt < K; kt += 64) {
#pragma unroll
    for (int i = 0; i < 4; i++) {
      const int row = i * 32 + srow;
      const char* ga = (const char*)(Ab + (m0 + row) * (long)lda + kt)
                       + (schx ^ ((row & 7) << 4));
      gld16(ga, (char*)lsA + i * 4096 + w * 1024);
    }
#pragma unroll
    for (int i = 0; i < 4; i++) {
      const int row = i * 32 + srow;
      const char* gb = (const char*)(Bb + (n0 + row) * (long)ldb + kt)
                       + (schx ^ ((row & 7) << 4));
      gld16(gb, (char*)lsB + i * 4096 + w * 1024);
    }
    __syncthreads();
#pragma unroll
    for (int h = 0; h < 2; h++) {
      bs8 af[4], bfr[4];
#pragma unroll
      for (int i = 0; i < 4; i++) {
        const int row = wr * 64 + i * 16 + (l & 15);
        const int byt = row * 128 + (((h * 64) + ((l >> 4) * 16)) ^ ((row & 7) << 4));
        af[i] = *(const bs8*)((const char*)lsA + byt);
      }
#pragma unroll
      for (int j = 0; j < 4; j++) {
        const int row = wc * 64 + j * 16 + (l & 15);
        const int byt = row * 128 + (((h * 64) + ((l >> 4) * 16)) ^ ((row & 7) << 4));
        bfr[j] = *(const bs8*)((const char*)lsB + byt);
      }
#pragma unroll
      for (int i = 0; i < 4; i++)
#pragma unroll
        for (int j = 0; j < 4; j++)
          acc[i][j] = __builtin_amdgcn_mfma_f32_16x16x32_bf16(af[i], bfr[j], acc[i][j], 0, 0, 0);
    }
    __syncthreads();
  }

  float bv[4] = {0.f, 0.f, 0.f, 0.f};
  if (bias) {
#pragma unroll
    for (int j = 0; j < 4; j++)
      bv[j] = inF(bias, (size_t)(n0 + wc * 64 + j * 16 + (l & 15)), bf);
  }
#pragma unroll
  for (int i = 0; i < 4; i++) {
#pragma unroll
    for (int j = 0; j < 4; j++) {
      const long rowb = m0 + wr * 64 + i * 16 + ((l >> 4) * 4);
      const long col = n0 + wc * 64 + j * 16 + (l & 15);
#pragma unroll
      for (int r = 0; r < 4; r++) {
        float v = acc[i][j][r] + bv[j];
        if (act == 1) v = tanhf(v);
        const long row = rowb + r;
        if (cmode == 0) {
          ((u16*)C)[bz * strideC + row * (long)ldc + col] = f2b(v);
        } else if (cmode == 1) {
          ((float*)C)[bz * strideC + row * (long)ldc + col] = v;
        } else {
          ((u16*)C)[((long)(row & 511) * 32 + (row >> 9)) * (long)ldc + col] = f2b(v);
        }
      }
    }
  }
}

// ---------------- masked softmax over T_ENC (in-place bf16) ----------------
__global__ __launch_bounds__(256) void k_softmax(
    u16* __restrict__ S, const int* __restrict__ lens) {
  const int m = blockIdx.x;
  const int b = m >> 9;
  const int len = lens[b];
  const int tid = threadIdx.x;
  const size_t base = (size_t)m * TENC;
  float v[4];
  float mx = -1e30f;
#pragma unroll
  for (int i = 0; i < 4; i++) {
    int j = tid + i * 256;
    float s = b2f(S[base + j]);
    v[i] = (j < len) ? s : -1e30f;
    mx = fmaxf(mx, v[i]);
  }
  __shared__ float red[8];
  for (int o = 32; o; o >>= 1) mx = fmaxf(mx, __shfl_xor(mx, o, 64));
  if ((tid & 63) == 0) red[tid >> 6] = mx;
  __syncthreads();
  mx = fmaxf(fmaxf(red[0], red[1]), fmaxf(red[2], red[3]));
  float e[4]; float sum = 0.f;
#pragma unroll
  for (int i = 0; i < 4; i++) {
    e[i] = (v[i] > -1e29f) ? expf(v[i] - mx) : 0.f;
    sum += e[i];
  }
  for (int o = 32; o; o >>= 1) sum += __shfl_xor(sum, o, 64);
  __shared__ float red2[8];
  if ((tid & 63) == 0) red2[tid >> 6] = sum;
  __syncthreads();
  sum = red2[0] + red2[1] + red2[2] + red2[3];
  const float inv = 1.f / sum;
#pragma unroll
  for (int i = 0; i < 4; i++) S[base + tid + i * 256] = f2b(e[i] * inv);
}

// ---------------- pack weights into per-block MFMA fragment order ----------------
// virtual col v = blk*32 + c16*16 + (lane&15); feature f=v>>2; slot=v&3
// fused=0 (L0): 128 blks, K=1024 (Whh; r,z,n,zero)           [blk][c16(2)][ks(32)][l][8] 64KB/blk
// fused=1 (L1): 128 blks, K=2048 ([Wih;Whh]; r,z,n_ih,n_hh)  [blk][c16(2)][ks(64)][l][8] 128KB/blk
__global__ __launch_bounds__(256) void k_packw(
    const void* __restrict__ Wih, const void* __restrict__ Whh,
    u16* __restrict__ out, int fused, const int* __restrict__ flagp) {
  const int bf = flagp[0];
  const long idx = (long)blockIdx.x * 256 + threadIdx.x;
  const int l = (int)(idx & 63);
  int ks, c16, blk;
  if (fused) { ks = (int)((idx >> 6) & 63); c16 = (int)((idx >> 12) & 1); blk = (int)(idx >> 13); }
  else       { ks = (int)((idx >> 6) & 31); c16 = (int)((idx >> 11) & 1); blk = (int)(idx >> 12); }
  const int v = blk * 32 + c16 * 16 + (l & 15);
  const int f = v >> 2, slot = v & 3;
  const int k = ks * 32 + ((l >> 4) << 3);
  const void* W = Whh; long row = 0; bool zero = false; int kk = k;
  if (!fused) {
    if (slot == 0) row = f;
    else if (slot == 1) row = 1024 + f;
    else if (slot == 2) row = 2048 + f;
    else zero = true;
  } else {
    const bool xp = (k < 1024); kk = k & 1023;
    W = xp ? Wih : Whh;
    if (slot == 0) row = f;
    else if (slot == 1) row = 1024 + f;
    else if (slot == 2) { row = 2048 + f; zero = !xp; }
    else { row = 2048 + f; zero = xp; }
  }
  u16 o[8];
#pragma unroll
  for (int e = 0; e < 8; e++)
    o[e] = zero ? (u16)0 : f2b(inF(W, (size_t)row * 1024 + kk + e, bf));
  ushort4* dst = (ushort4*)(out + idx * 8);
  dst[0] = make_ushort4(o[0], o[1], o[2], o[3]);
  dst[1] = make_ushort4(o[4], o[5], o[6], o[7]);
}

// ---------------- persistent 2-layer GRU (round-14 structure, verbatim) ----------------
// stage one 64KB image: 16 direct-to-LDS coherent issues; NO drain here (caller drains once)
__device__ __forceinline__ void stage64_issue(const char* src, char* dst, int l, int w) {
#pragma unroll
  for (int i = 0; i < 16; i++) {
    const int off = i * 4096 + w * 1024;
    gld16c(src + off + l * 16, dst + off);
  }
}
__device__ __forceinline__ void waitpair(u32* flags, int aL0, int aL1, int tid) {
  if (tid < 64) {
    int guard = 0;
    while (1) {
      const int v0 = (int)aLoad(flags + (size_t)tid * FS);
      const int v1 = (int)aLoad(flags + (size_t)(tid + 64) * FS);
      const int v2 = (int)aLoad(flags + (size_t)(tid + 128) * FS);
      const int v3 = (int)aLoad(flags + (size_t)(tid + 192) * FS);
      const bool ok = (v0 >= aL0) && (v1 >= aL0) && (v2 >= aL1) && (v3 >= aL1);
      if (__all(ok)) break;
      if (++guard > POLL_CAP) break;
      __builtin_amdgcn_s_sleep(1);
    }
  }
  __syncthreads();
}

__global__ void __launch_bounds__(256, 1) k_gru_p(
    const u16* __restrict__ xp0, const u16* __restrict__ wpk0, const u16* __restrict__ wpk1,
    const void* __restrict__ bhh0, const void* __restrict__ bih1, const void* __restrict__ bhh1,
    u16* __restrict__ y1, char* h0buf, char* h1buf, u32* flags,
    const int* __restrict__ flagp) {
  extern __shared__ char smem[];            // L0: [W 64K][img 64K][red]; L1: [img 128K][red]
  float* red = (float*)(smem + 131072);
  const int bf = flagp[0];
  const int tid = threadIdx.x, l = tid & 63, w = tid >> 6;
  const int nh = w & 1, kh = w >> 1;
  const int g = blockIdx.x;
  const bool isL0 = (g < 128);
  const int gg = isL0 ? g : g - 128;
  const int fl = (l & 15) >> 2;
  const int F = gg * 8 + nh * 4 + fl;
  const int bl0 = (l & 48) | (fl << 2);

  float hprev[2][4] = {{0.f, 0.f, 0.f, 0.f}, {0.f, 0.f, 0.f, 0.f}};

  if (isL0) {
    {  // ONE-TIME: stage 64KB Whh slice into LDS (normal cached DMA)
      const char* wsrc = (const char*)(wpk0 + (size_t)gg * 32768);
#pragma unroll
      for (int i = 0; i < 16; i++) {
        const int off = i * 4096 + w * 1024;
        gld16(wsrc + off + l * 16, smem + off);
      }
    }
    __syncthreads();
    const char* Wl = smem;         // 64KB weights (LDS)
    char* img = smem + 65536;      // 64KB h image
    const float br = inF(bhh0, (size_t)F, bf);
    const float bz = inF(bhh0, (size_t)(1024 + F), bf);
    const float bn = inF(bhh0, (size_t)(2048 + F), bf);
    for (int t = 0; t < TSEQ; t++) {
      waitpair(flags, t, t - 1, tid);           // own grp done t-1; L1 freed slot
      stage64_issue(h0buf + (t & 1) * 65536, img, l, w);
      waitVM0();
      __syncthreads();
      f4_t S[2] = {};
#pragma unroll 4
      for (int ksl = 0; ksl < 16; ksl++) {
        const int ks = kh * 16 + ksl;
        const bs8 bb = *(const bs8*)(Wl + (((size_t)(nh * 32 + ks) * 64 + l) << 4));
#pragma unroll
        for (int mt = 0; mt < 2; mt++) {
          const int row = mt * 16 + (l & 15);
          const int byt = row * 2048 + ((ks * 64 + ((l >> 4) << 4)) ^ ((row & 7) << 4));
          const bs8 aa = *(const bs8*)(img + byt);
          S[mt] = __builtin_amdgcn_mfma_f32_16x16x32_bf16(aa, bb, S[mt], 0, 0, 0);
        }
      }
      if (kh == 1) {
#pragma unroll
        for (int mt = 0; mt < 2; mt++)
          *(f4_t*)&red[((nh * 2 + mt) * 64 + l) * 4] = S[mt];
      }
      __syncthreads();
      if (kh == 0) {
#pragma unroll
        for (int mt = 0; mt < 2; mt++)
          S[mt] += *(const f4_t*)&red[((nh * 2 + mt) * 64 + l) * 4];
        char* hw = h0buf + ((t + 1) & 1) * 65536;
#pragma unroll
        for (int mt = 0; mt < 2; mt++) {
#pragma unroll
          for (int r = 0; r < 4; r++) {
            const int b = mt * 16 + ((l >> 4) << 2) + r;
            const float hr = __shfl(S[mt][r], bl0);
            const float hz = __shfl(S[mt][r], bl0 + 1);
            const float hn = __shfl(S[mt][r], bl0 + 2);
            const long xb = (long)t * 98304 + (long)b * 3072 + F;
            const float xr = b2f(xp0[xb]);
            const float xz = b2f(xp0[xb + 1024]);
            const float xn = b2f(xp0[xb + 2048]);
            const float rr = 1.f / (1.f + expf(-(xr + hr + br)));
            const float zz = 1.f / (1.f + expf(-(xz + hz + bz)));
            const float nn = tanhf(xn + rr * (hn + bn));
            const float hv = (1.f - zz) * nn + zz * hprev[mt][r];
            hprev[mt][r] = hv;
            if ((l & 3) == 0) {
              const int swb = b * 2048 + ((2 * F) ^ ((b & 7) << 4));
              stUCshort(hw + swb, (u32)f2b(hv));
            }
          }
        }
      }
      waitVM0();
      __syncthreads();
      if (tid == 0) aStore(flags + (size_t)g * FS, (u32)(t + 1));
    }
  } else {
    const char* W = (const char*)(wpk1 + (size_t)gg * 65536);  // 128KB slice (L2)
    for (int s = 0; s < TSEQ; s++) {
      const float br = inF(bih1, (size_t)F, bf) + inF(bhh1, (size_t)F, bf);
      const float bz = inF(bih1, (size_t)(1024 + F), bf) + inF(bhh1, (size_t)(1024 + F), bf);
      const float bxn = inF(bih1, (size_t)(2048 + F), bf);
      const float bhn = inF(bhh1, (size_t)(2048 + F), bf);
      waitpair(flags, s + 1, s, tid);           // y0[s]=h0(s+1) ready; own grp done s-1
      stage64_issue(h0buf + ((s + 1) & 1) * 65536, smem, l, w);        // y0 image
      stage64_issue(h1buf + (s & 1) * 65536, smem + 65536, l, w);      // h1 image
      waitVM0();
      __syncthreads();
      f4_t S[2] = {};
#pragma unroll 4
      for (int ksl = 0; ksl < 32; ksl++) {
        const int ks = kh * 32 + ksl;
        const bs8 bb = *(const bs8*)(W + (((size_t)(nh * 64 + ks) * 64 + l) << 4));
        const int base = (ks >= 32) ? 65536 : 0;
        const int ks5 = ks & 31;
#pragma unroll
        for (int mt = 0; mt < 2; mt++) {
          const int row = mt * 16 + (l & 15);
          const int byt = base + row * 2048 + ((ks5 * 64 + ((l >> 4) << 4)) ^ ((row & 7) << 4));
          const bs8 aa = *(const bs8*)(smem + byt);
          S[mt] = __builtin_amdgcn_mfma_f32_16x16x32_bf16(aa, bb, S[mt], 0, 0, 0);
        }
      }
      if (kh == 1) {
#pragma unroll
        for (int mt = 0; mt < 2; mt++)
          *(f4_t*)&red[((nh * 2 + mt) * 64 + l) * 4] = S[mt];
      }
      __syncthreads();
      if (kh == 0) {
#pragma unroll
        for (int mt = 0; mt < 2; mt++)
          S[mt] += *(const f4_t*)&red[((nh * 2 + mt) * 64 + l) * 4];
        char* hw = h1buf + ((s + 1) & 1) * 65536;
#pragma unroll
        for (int mt = 0; mt < 2; mt++) {
#pragma unroll
          for (int r = 0; r < 4; r++) {
            const int b = mt * 16 + ((l >> 4) << 2) + r;
            const float rs = __shfl(S[mt][r], bl0);
            const float zs = __shfl(S[mt][r], bl0 + 1);
            const float xnp = __shfl(S[mt][r], bl0 + 2);
            const float hnp = __shfl(S[mt][r], bl0 + 3);
            const float rr = 1.f / (1.f + expf(-(rs + br)));
            const float zz = 1.f / (1.f + expf(-(zs + bz)));
            const float nn = tanhf((xnp + bxn) + rr * (hnp + bhn));
            const float hv = (1.f - zz) * nn + zz * hprev[mt][r];
            hprev[mt][r] = hv;
            if ((l & 3) == 0) {
              const int swb = b * 2048 + ((2 * F) ^ ((b & 7) << 4));
              stUCshort(hw + swb, (u32)f2b(hv));
              y1[((long)b * 512 + s) * 1024 + F] = f2b(hv);   // normal store
            }
          }
        }
      }
      waitVM0();
      __syncthreads();
      if (tid == 0) aStore(flags + (size_t)g * FS, (u32)(s + 1));
    }
  }
}

// ---------------- log_softmax over V ----------------
__global__ __launch_bounds__(256) void k_logsoftmax(
    const float* __restrict__ L, void* __restrict__ out, const int* __restrict__ flagp) {
  const int bf = flagp[0];
  const int m = blockIdx.x;
  const int tid = threadIdx.x;
  const size_t base = (size_t)m * VOC;
  float v0 = L[base + tid], v1 = L[base + tid + 256];
  float mx = fmaxf(v0, v1);
  __shared__ float red[8];
  for (int o = 32; o; o >>= 1) mx = fmaxf(mx, __shfl_xor(mx, o, 64));
  if ((tid & 63) == 0) red[tid >> 6] = mx;
  __syncthreads();
  mx = fmaxf(fmaxf(red[0], red[1]), fmaxf(red[2], red[3]));
  float s = expf(v0 - mx) + expf(v1 - mx);
  for (int o = 32; o; o >>= 1) s += __shfl_xor(s, o, 64);
  __shared__ float red2[8];
  if ((tid & 63) == 0) red2[tid >> 6] = s;
  __syncthreads();
  s = red2[0] + red2[1] + red2[2] + red2[3];
  const float lse = mx + logf(s);
  outF(out, base + tid, v0 - lse, bf);
  outF(out, base + tid + 256, v1 - lse, bf);
}

extern "C" void kernel_launch(void* const* d_in, const int* in_sizes, int n_in,
                              void* d_out, int out_size, void* d_ws, size_t ws_size,
                              hipStream_t stream) {
  const void* enc = d_in[0];
  const int* lens = (const int*)d_in[1];
  const int* labels = (const int*)d_in[2];
  const void* emb = d_in[3];
  const void* lin_in = d_in[4];
  const void* lin_out = d_in[5];
  const void* w_ih0 = d_in[6];
  const void* w_hh0 = d_in[7];
  const void* b_ih0 = d_in[8];
  const void* b_hh0 = d_in[9];
  const void* w_ih1 = d_in[10];
  const void* w_hh1 = d_in[11];
  const void* b_ih1 = d_in[12];
  const void* b_hh1 = d_in[13];
  const void* fc_w = d_in[14];
  const void* fc_b = d_in[15];

  char* ws = (char*)d_ws;
  const size_t SZ = (size_t)NB * TSEQ * HD * 2;   // 33,554,432
  int* flag = (int*)ws;
  u16* R0 = (u16*)(ws + 256);                     // x -> encT -> attn
  u16* R1 = (u16*)(ws + 256 + SZ);                // enc_bf -> wih0_bf
  u16* R2 = (u16*)(ws + 256 + 2 * SZ);            // combined -> [y1 | packs + h]
  char* R4 = ws + 256 + 4 * SZ;                   // scores+wli/wlo -> xp0 -> wfc+logits

  char* R2u = (char*)R2 + SZ;
  u16* wpk0 = (u16*)R2u;                          // 8 MB  (128 blk x 64KB)
  u16* wpk1 = (u16*)(R2u + 8388608);              // 16 MB (128 blk x 128KB)
  char* hreg = R2u + 25165824;
  u32* flagsbuf = (u32*)hreg;                     // 256*128B = 32KB
  char* h0buf = hreg + 32768;                     // 2 x 64KB parity
  char* h1buf = hreg + 32768 + 131072;            // 2 x 64KB parity
  const size_t hreg_bytes = 32768 + 262144;

  u16* scores = (u16*)R4;
  u16* wli = (u16*)(R4 + 35651584);
  u16* wlo = (u16*)(R4 + 37748736);
  u16* xp0 = (u16*)R4;                            // [t][b][3072] bf16, 96MB
  u16* wfc = (u16*)R4;                            // post-GRU, 1MB
  float* logits = (float*)(R4 + 1048576);         // post-GRU, 33.5MB f32

  k_detect<<<1, 256, 0, stream>>>((const u32*)emb, flag);
  k_embed<<<NB * TSEQ, 256, 0, stream>>>(labels, emb, R0, flag);
  k_f2bf<<<32768, 256, 0, stream>>>(enc, R1, flag);
  k_f2bf<<<1024, 256, 0, stream>>>(lin_in, wli, flag);
  k_f2bf<<<2048, 256, 0, stream>>>(lin_out, wlo, flag);

  // q = x @ lin_in^T -> combined right half
  k_mfma_gemm<<<dim3(128, 8, 1), 256, 0, stream>>>(
      R0, wli, HD, HD, HD, 0, 0, 0, (void*)(R2 + 1024), 2 * HD, 0, 0, nullptr, flag);
  // encT (x dead)
  k_transpose<<<dim3(32, 32, NB), 256, 0, stream>>>(enc, R0, flag);
  // scores[b] = q[b] @ enc_bf[b]^T
  k_mfma_gemm<<<dim3(4, 8, NB), 256, 0, stream>>>(
      R2 + 1024, R1, HD, 2 * HD, HD,
      (long)TSEQ * 2 * HD, (long)TENC * HD, (long)TSEQ * TENC,
      (void*)scores, TENC, 0, 0, nullptr, flag);
  k_softmax<<<NB * TSEQ, 256, 0, stream>>>(scores, lens);
  // mix[b] = w[b] @ encT[b]^T -> combined left half
  k_mfma_gemm<<<dim3(4, 8, NB), 256, 0, stream>>>(
      scores, R0, TENC, TENC, TENC,
      (long)TSEQ * TENC, (long)HD * TENC, (long)TSEQ * 2 * HD,
      (void*)R2, 2 * HD, 0, 0, nullptr, flag);
  // attn = tanh(combined @ lin_out^T) -> R0 row-major (encT dead)
  k_mfma_gemm<<<dim3(128, 8, 1), 256, 0, stream>>>(
      R2, wlo, 2 * HD, 2 * HD, 2 * HD, 0, 0, 0,
      (void*)R0, HD, 0, 1, nullptr, flag);

  // weight packs (combined dead -> R2 upper free)
  k_packw<<<2048, 256, 0, stream>>>(nullptr, w_hh0, wpk0, 0, flag);
  k_packw<<<4096, 256, 0, stream>>>(w_ih1, w_hh1, wpk1, 1, flag);
  // w_ih0 bf16 (enc_bf dead)
  k_f2bf<<<3072, 256, 0, stream>>>(w_ih0, R1, flag);
  // xp0 = attn @ w_ih0^T + b_ih0, t-major (overwrites scores/wli/wlo - all dead)
  k_mfma_gemm<<<dim3(128, 24, 1), 256, 0, stream>>>(
      R0, R1, HD, HD, HD, 0, 0, 0, (void*)xp0, 3 * HD, 2, 0, b_ih0, flag);

  // persistent fence-free GRU (flags barrier; coherent DMA staging; L0 W in LDS)
  hipMemsetAsync(hreg, 0, hreg_bytes, stream);
  hipFuncSetAttribute((const void*)k_gru_p,
                      hipFuncAttributeMaxDynamicSharedMemorySize, 139264);
  u16* y1p = R2;
  void* args[] = {&xp0, &wpk0, &wpk1,
                  (void*)&b_hh0, (void*)&b_ih1, (void*)&b_hh1,
                  &y1p, &h0buf, &h1buf, &flagsbuf, &flag};
  hipLaunchCooperativeKernel((const void*)k_gru_p, dim3(256), dim3(256),
                             args, 139264, stream);

  // logits = y1 @ fc_w^T + fc_b (xp0 dead)
  k_f2bf<<<512, 256, 0, stream>>>(fc_w, wfc, flag);
  k_mfma_gemm<<<dim3(128, 4, 1), 256, 0, stream>>>(
      R2, wfc, HD, HD, HD, 0, 0, 0, (void*)logits, VOC, 1, 0, fc_b, flag);
  k_logsoftmax<<<NB * TSEQ, 256, 0, stream>>>(logits, d_out, flag);
}